// Round 14
// baseline (120.760 us; speedup 1.0000x reference)
//
#include <hip/hip_runtime.h>
#include <hip/hip_fp16.h>

#define NH 12
#define BSZ 8
#define NSEQ 1024
#define EDIM 768
#define DH 64

typedef _Float16 f16;
typedef f16 half8 __attribute__((ext_vector_type(8)));
typedef f16 half4 __attribute__((ext_vector_type(4)));
typedef float f32x4 __attribute__((ext_vector_type(4)));
typedef unsigned int u32;
typedef u32 u32x2 __attribute__((ext_vector_type(2)));

static __device__ __forceinline__ void gload16(const void* g, void* l) {
    __builtin_amdgcn_global_load_lds((const __attribute__((address_space(1))) u32*)g,
                                     (__attribute__((address_space(3))) u32*)l, 16, 0, 0);
}
static __device__ __forceinline__ u32 pkrtz(float a, float b) {
    auto h = __builtin_amdgcn_cvt_pkrtz(a, b);
    return __builtin_bit_cast(u32, h);
}
#define MFMA16(a, b, c) __builtin_amdgcn_mfma_f32_16x16x32_f16((a), (b), (c), 0, 0, 0)

// ---------------- fused fp32 -> fp16 convert (x | w_qkv | w_proj) ----------------
__global__ void cvt_all_kernel(const float* __restrict__ x, const float* __restrict__ wq,
                               const float* __restrict__ wp, f16* __restrict__ dst) {
    const int NX = BSZ * NSEQ * EDIM;
    const int NWQ = 3 * EDIM * EDIM;
    int i = (blockIdx.x * blockDim.x + threadIdx.x) * 4;
    const float* s;
    int j;
    if (i < NX) { s = x; j = i; }
    else if (i < NX + NWQ) { s = wq; j = i - NX; }
    else { s = wp; j = i - NX - NWQ; }
    float4 v = *(const float4*)(s + j);
    half4 o = { (f16)v.x, (f16)v.y, (f16)v.z, (f16)v.w };
    *(half4*)(dst + i) = o;
}

// ---------------- GEMM: C[m][c] = sum_k A[m][k]*W[c][k] + bias[c] ----------------
// 128(M) x 256(N) x 32(K) tile, 512 threads / 8 waves (2M x 4N), 4x4 frags/wave.
// Fragment-order LDS (lane-linear ds_read_b128, conflict-free). 3-buffer
// rotation, ONE barrier per K-step: buf[(kt+2)%3] was read at step kt-1, and
// the top-of-step-kt barrier proves those reads drained (lgkmcnt(0) precedes
// the MFMAs that precede the barrier). vmcnt(3) = 2-step latency cover.
// XCD-pinned grid. MODE 0: scatter q/k/v. MODE 1: nkt = 2*active_heads.
template<int MODE>
__global__ __launch_bounds__(512) void gemm_kernel(
    const f16* __restrict__ A, const f16* __restrict__ Wt, const float* __restrict__ bias,
    f16* __restrict__ qbuf, f16* __restrict__ kbuf, f16* __restrict__ vbuf,
    float* __restrict__ outp, const int* __restrict__ activep, int Kd, int NCd)
{
    __shared__ __align__(16) f16 Ah[3][2][4][64][8];   // [buf][wrh][fm][lane][8] 24 KB
    __shared__ __align__(16) f16 Bh[3][4][4][64][8];   // [buf][wch][fn][lane][8] 48 KB

    constexpr int K = EDIM;           // 768 for both GEMMs
    constexpr int NKT = K / 32;       // 24
    constexpr int NB = (MODE == 0) ? 9 : 3;   // 256-wide col tiles

    const int lin = blockIdx.x;
    const int xcd = lin & 7, pos = lin >> 3;
    const int bx = pos % NB;
    const int my = xcd + (pos / NB) * 8;
    const int c0 = bx * 256;
    const int m0 = my * 128;
    const int ah = *activep;
    if (MODE == 0) {
        if (((c0 % EDIM) >> 6) >= ah) return;   // all 4 heads of this tile masked
    }
    const int nkt = (MODE == 1) ? (2 * ah) : NKT;   // MODE 1: skip zero ctx cols
    const int tid = threadIdx.x;
    const int lane = tid & 63;
    const int wid  = tid >> 6;        // 0..7
    const int wr = wid >> 2;          // M half (0..1)
    const int wc = wid & 3;           // N quarter (0..3)
    const int r16 = lane & 15, rg = lane >> 4;

    f32x4 acc[4][4];
#pragma unroll
    for (int i = 0; i < 4; ++i)
#pragma unroll
        for (int j = 0; j < 4; ++j)
            acc[i][j] = f32x4{0.f, 0.f, 0.f, 0.f};

    // staging assignment: wave stages 1 A-slab (id=wid) + 2 B-slabs (2wid, 2wid+1)
    const int awrh = wid >> 2, afm = wid & 3;
    const int ib0 = 2 * wid, ib1 = 2 * wid + 1;
    const f16* gAs  = A  + (size_t)(m0 + awrh * 64 + afm * 16 + r16) * K + rg * 8;
    const f16* gBs0 = Wt + (size_t)(c0 + (ib0 >> 2) * 64 + (ib0 & 3) * 16 + r16) * K + rg * 8;
    const f16* gBs1 = Wt + (size_t)(c0 + (ib1 >> 2) * 64 + (ib1 & 3) * 16 + r16) * K + rg * 8;

    auto stage = [&](int buf, int kt) {
        gload16(gAs  + kt * 32, &Ah[buf][awrh][afm][0][0]);
        gload16(gBs0 + kt * 32, &Bh[buf][ib0 >> 2][ib0 & 3][0][0]);
        gload16(gBs1 + kt * 32, &Bh[buf][ib1 >> 2][ib1 & 3][0][0]);
    };

    if (nkt > 0) stage(0, 0);
    if (nkt > 1) stage(1, 1);

    int cur = 0;
#pragma unroll 1
    for (int kt = 0; kt < nkt; ++kt) {
        if (kt + 1 < nkt) asm volatile("s_waitcnt vmcnt(3)" ::: "memory");  // tile kt landed
        else              asm volatile("s_waitcnt vmcnt(0)" ::: "memory");  // drain tail
        __builtin_amdgcn_s_barrier();            // all waves done with buf[(kt+2)%3] reads
        __builtin_amdgcn_sched_barrier(0);
        if (kt + 2 < nkt) {
            const int nb = (cur + 2 >= 3) ? cur - 1 : cur + 2;
            stage(nb, kt + 2);                   // refill the buffer vacated at kt-1
        }
        __builtin_amdgcn_sched_barrier(0);
        half8 af[4], bf[4];
#pragma unroll
        for (int f = 0; f < 4; ++f) {
            af[f] = *(const half8*)&Ah[cur][wr][f][lane][0];
            bf[f] = *(const half8*)&Bh[cur][wc][f][lane][0];
        }
        asm volatile("s_waitcnt lgkmcnt(0)" ::: "memory");
        __builtin_amdgcn_sched_barrier(0);
        __builtin_amdgcn_s_setprio(1);
#pragma unroll
        for (int fm = 0; fm < 4; ++fm)
#pragma unroll
            for (int fn = 0; fn < 4; ++fn)
                acc[fm][fn] = MFMA16(af[fm], bf[fn], acc[fm][fn]);
        __builtin_amdgcn_s_setprio(0);
        cur = (cur == 2) ? 0 : cur + 1;
    }

    // epilogue: C/D layout col=lane&15, row=(lane>>4)*4+reg
#pragma unroll
    for (int fn = 0; fn < 4; ++fn) {
        const int c = c0 + wc * 64 + fn * 16 + r16;
        const float bv = bias[c];
        const bool colActive = (MODE == 1) || (((c % EDIM) >> 6) < ah);
#pragma unroll
        for (int fm = 0; fm < 4; ++fm) {
            const int mbase = m0 + wr * 64 + fm * 16 + rg * 4;
#pragma unroll
            for (int r = 0; r < 4; ++r) {
                const float val = acc[fm][fn][r] + bv;
                const int m = mbase + r;
                if (MODE == 1) {
                    outp[(size_t)m * EDIM + c] = val;
                } else if (colActive) {
                    const int s  = c / EDIM;
                    const int cc = c % EDIM;
                    const int hh = cc >> 6, d = cc & 63;
                    const int bb = m >> 10, n = m & 1023;
                    f16* dst = (s == 0) ? qbuf : ((s == 1) ? kbuf : vbuf);
                    dst[(((size_t)bb * NH + hh) * NSEQ + n) * DH + d] = (f16)val;
                }
            }
        }
    }
}

// ---------------- V transpose: vbuf [b][h][n][d] -> vtb [b][h][d][n] ----------------
__global__ __launch_bounds__(256) void vtrans_kernel(const f16* __restrict__ vbuf,
                                                     f16* __restrict__ vtb,
                                                     const int* __restrict__ activep) {
    const int b = blockIdx.z, h = blockIdx.y;
    if (h >= *activep) return;
    const int n0 = blockIdx.x * 64;
    __shared__ __align__(16) f16 T[64][72];
    const f16* src = vbuf + (((size_t)b * NH + h) * NSEQ + n0) * DH;
    f16* dst = vtb + ((size_t)b * NH + h) * DH * NSEQ;
    const int t = threadIdx.x;
    const int rn = t >> 2, rc = t & 3;
    *(half8*)&T[rn][rc * 16]     = *(const half8*)&src[(size_t)rn * DH + rc * 16];
    *(half8*)&T[rn][rc * 16 + 8] = *(const half8*)&src[(size_t)rn * DH + rc * 16 + 8];
    __syncthreads();
    const int d = t >> 2, nc = (t & 3) * 16;
    half8 o0, o1;
#pragma unroll
    for (int j = 0; j < 8; ++j) {
        o0[j] = T[nc + j][d];
        o1[j] = T[nc + 8 + j][d];
    }
    *(half8*)&dst[(size_t)d * NSEQ + n0 + nc]     = o0;
    *(half8*)&dst[(size_t)d * NSEQ + n0 + nc + 8] = o1;
}

// ---------------- flash attention: 128-row Q block, 8 waves share K/V tiles ----------------
__global__ __launch_bounds__(512) void attn_kernel(
    const f16* __restrict__ qbuf, const f16* __restrict__ kbuf, const f16* __restrict__ vtb,
    f16* __restrict__ ctx, const int* __restrict__ activep)
{
    __shared__ __align__(16) f16 Kh[2][64][64];   // 16 KB
    __shared__ __align__(16) f16 Vh[2][64][64];   // 16 KB  (swizzled V^T tile: row d, 64 k)
    __shared__ __align__(16) f16 Ph[8][16][64];   // 16 KB  per-wave P, swizzled

    const int b = blockIdx.z, h = blockIdx.y;
    const int q0 = blockIdx.x * 128;
    const int tid = threadIdx.x, lane = tid & 63, wid = tid >> 6;

    if (h >= *activep) return;   // masked head: ctx region never read (gemm1 truncated)

    const size_t hb = (((size_t)b * NH + h) * NSEQ) * DH;
    const f16* Q  = qbuf + hb;
    const char* Kp = (const char*)(kbuf + hb);
    const char* Vp = (const char*)(vtb + hb);   // rows d, stride NSEQ*2 bytes

    const int ql = lane & 15;
    const int g  = lane >> 4;
    const int q7 = ql & 7;

    // Q B-fragment, pre-scaled by 0.125*log2(e): scores arrive in log2 domain,
    // so softmax uses native exp2 (no per-score multiply).
    half8 qb0, qb1;
    {
        const f16 qsc = (f16)0.18033688f;
        const f16* qp = Q + (size_t)(q0 + wid * 16 + ql) * DH + g * 8;
        qb0 = *(const half8*)qp        * qsc;
        qb1 = *(const half8*)(qp + 32) * qsc;
    }
    const half8 ones = { (f16)1, (f16)1, (f16)1, (f16)1, (f16)1, (f16)1, (f16)1, (f16)1 };

    // staging: waves 0-3 stage K (16 rows each), waves 4-7 stage V^T (16 rows each)
    // pre-swizzled global source (chunk ^= row&7), linear gload_lds dest
    const int srow8 = lane >> 3;                 // row within 8-row group
    const int schk  = (lane & 7) ^ srow8;        // swizzled source chunk
    const int qh4   = wid & 3;                   // 16-row chunk id

    auto stage = [&](int buf, int kt) {
        if (wid < 4) {
            const char* kb = Kp + (size_t)kt * 8192;        // 64 rows * 128B
#pragma unroll
            for (int i = 0; i < 2; ++i) {
                const int r = qh4 * 16 + i * 8 + srow8;
                gload16(kb + (size_t)r * 128 + schk * 16, &Kh[buf][qh4 * 16 + i * 8][0]);
            }
        } else {
#pragma unroll
            for (int i = 0; i < 2; ++i) {
                const int r = qh4 * 16 + i * 8 + srow8;
                gload16(Vp + (size_t)r * (NSEQ * 2) + (size_t)kt * 128 + schk * 16,
                        &Vh[buf][qh4 * 16 + i * 8][0]);
            }
        }
    };

    f32x4 oacc[4];
#pragma unroll
    for (int i = 0; i < 4; ++i) oacc[i] = f32x4{0.f, 0.f, 0.f, 0.f};
    f32x4 lacc = f32x4{0.f, 0.f, 0.f, 0.f};   // row-sums of P, same row layout as oacc
    float mr = -INFINITY;

    char* prow = (char*)&Ph[wid][ql][0];

    stage(0, 0);
    const int NT = NSEQ / 64;
    for (int kt = 0; kt < NT; ++kt) {
        const int cur = kt & 1;
        __syncthreads();                     // cur's loads landed; prev reads done
        if (kt + 1 < NT) stage(cur ^ 1, kt + 1);   // fly during compute below

        // S^T = K Q^T : st[s][r] = S^T[k=16s+4g+r][q=ql]  (log2 domain)
        f32x4 st[4];
        __builtin_amdgcn_s_setprio(1);
#pragma unroll
        for (int s = 0; s < 4; ++s) {
            f32x4 t = f32x4{0.f, 0.f, 0.f, 0.f};
            t = MFMA16(*(const half8*)((const char*)&Kh[cur][16 * s + ql][0] + ((g ^ q7) << 4)),       qb0, t);
            t = MFMA16(*(const half8*)((const char*)&Kh[cur][16 * s + ql][0] + (((4 | g) ^ q7) << 4)), qb1, t);
            st[s] = t;
        }
        __builtin_amdgcn_s_setprio(0);

        // row max: nested triples -> v_max3_f32, then 2 shuffles
        float a0 = fmaxf(fmaxf(st[0][0], st[0][1]), st[0][2]);
        float a1 = fmaxf(fmaxf(st[0][3], st[1][0]), st[1][1]);
        float a2 = fmaxf(fmaxf(st[1][2], st[1][3]), st[2][0]);
        float a3 = fmaxf(fmaxf(st[2][1], st[2][2]), st[2][3]);
        float a4 = fmaxf(fmaxf(st[3][0], st[3][1]), st[3][2]);
        float pmax = fmaxf(fmaxf(fmaxf(a0, a1), fmaxf(a2, a3)), fmaxf(a4, st[3][3]));
        pmax = fmaxf(pmax, __shfl_xor(pmax, 16));
        pmax = fmaxf(pmax, __shfl_xor(pmax, 32));

        // online softmax (log2 domain, unconditional rescale)
        const float mnew = fmaxf(mr, pmax);
        const float sc = exp2f(mr - mnew);
#pragma unroll
        for (int s = 0; s < 4; ++s)
#pragma unroll
            for (int r = 0; r < 4; ++r)
                st[s][r] = exp2f(st[s][r] - mnew);   // native v_exp_f32
        mr = mnew;

        // rescale O and l accumulators (C rows are q = 4g + r)
#pragma unroll
        for (int r = 0; r < 4; ++r) {
            const float scr = __shfl(sc, (g << 2) | r);
            oacc[0][r] *= scr; oacc[1][r] *= scr; oacc[2][r] *= scr; oacc[3][r] *= scr;
            lacc[r] *= scr;
        }

        // P -> per-wave swizzled LDS: row ql, halves k = 16s+4g .. +3
#pragma unroll
        for (int s = 0; s < 4; ++s) {
            u32x2 w = { pkrtz(st[s][0], st[s][1]), pkrtz(st[s][2], st[s][3]) };
            *(u32x2*)(prow + ((32 * s + 8 * g) ^ (q7 << 4))) = w;
        }
        const half8 pa0 = *(const half8*)(prow + ((16 * g) ^ (q7 << 4)));
        const half8 pa1 = *(const half8*)(prow + ((64 + 16 * g) ^ (q7 << 4)));

        // O += P V ; l += P 1  (row-sum via ones-MFMA, no shuffles)
        __builtin_amdgcn_s_setprio(1);
        lacc = MFMA16(pa0, ones, lacc);
        lacc = MFMA16(pa1, ones, lacc);
#pragma unroll
        for (int db = 0; db < 4; ++db) {
            oacc[db] = MFMA16(pa0, *(const half8*)((const char*)&Vh[cur][16 * db + ql][0] + ((g ^ q7) << 4)),       oacc[db]);
            oacc[db] = MFMA16(pa1, *(const half8*)((const char*)&Vh[cur][16 * db + ql][0] + (((4 | g) ^ q7) << 4)), oacc[db]);
        }
        __builtin_amdgcn_s_setprio(0);
    }

    // epilogue: rows q = 4g + r, cols d = db*16 + ql ; l already in row layout
#pragma unroll
    for (int r = 0; r < 4; ++r) {
        const float li = 1.0f / lacc[r];
        const int n = q0 + wid * 16 + (g << 2) + r;
#pragma unroll
        for (int db = 0; db < 4; ++db)
            ctx[((size_t)b * NSEQ + n) * EDIM + h * DH + db * 16 + ql] = (f16)(oacc[db][r] * li);
    }
}

// ---------------- launch ----------------
extern "C" void kernel_launch(void* const* d_in, const int* in_sizes, int n_in,
                              void* d_out, int out_size, void* d_ws, size_t ws_size,
                              hipStream_t stream) {
    const float* x      = (const float*)d_in[0];
    const float* w_qkv  = (const float*)d_in[1];
    const float* b_qkv  = (const float*)d_in[2];
    const float* w_proj = (const float*)d_in[3];
    const float* b_proj = (const float*)d_in[4];
    const int*   active = (const int*)d_in[5];
    float* out = (float*)d_out;

    char* ws = (char*)d_ws;
    const size_t n_x  = (size_t)BSZ * NSEQ * EDIM;       // 6291456
    const size_t n_wq = (size_t)3 * EDIM * EDIM;         // 1769472
    const size_t n_wp = (size_t)EDIM * EDIM;             // 589824
    const size_t n_hd = (size_t)BSZ * NH * NSEQ * DH;    // 6291456 per q/k/v

    f16* xh   = (f16*)ws;
    f16* wqh  = xh + n_x;
    f16* wph  = wqh + n_wq;
    f16* qh   = wph + n_wp;
    f16* kh   = qh + n_hd;
    f16* vh   = kh + n_hd;
    f16* ctxh = vh + n_hd;
    f16* vtb  = xh;   // alias: xh is dead after gemm<0>; n_x == n_hd

    const size_t n_cvt = n_x + n_wq + n_wp;
    cvt_all_kernel<<<(int)(n_cvt / 4 / 256), 256, 0, stream>>>(x, w_qkv, w_proj, xh);

    gemm_kernel<0><<<dim3(64 * 9), 512, 0, stream>>>(
        xh, wqh, b_qkv, qh, kh, vh, nullptr, active, EDIM, 3 * EDIM);

    vtrans_kernel<<<dim3(NSEQ / 64, NH, BSZ), 256, 0, stream>>>(vh, vtb, active);

    attn_kernel<<<dim3(NSEQ / 128, NH, BSZ), 512, 0, stream>>>(qh, kh, vtb, ctxh, active);

    gemm_kernel<1><<<dim3(64 * 3), 512, 0, stream>>>(
        ctxh, wph, b_proj, nullptr, nullptr, nullptr, out, active, EDIM, EDIM);
}

// Round 15
// 117.991 us; speedup vs baseline: 1.0235x; 1.0235x over previous
//
#include <hip/hip_runtime.h>
#include <hip/hip_fp16.h>

#define NH 12
#define BSZ 8
#define NSEQ 1024
#define EDIM 768
#define DH 64

typedef _Float16 f16;
typedef f16 half8 __attribute__((ext_vector_type(8)));
typedef f16 half4 __attribute__((ext_vector_type(4)));
typedef float f32x4 __attribute__((ext_vector_type(4)));
typedef unsigned int u32;
typedef u32 u32x2 __attribute__((ext_vector_type(2)));

static __device__ __forceinline__ void gload16(const void* g, void* l) {
    __builtin_amdgcn_global_load_lds((const __attribute__((address_space(1))) u32*)g,
                                     (__attribute__((address_space(3))) u32*)l, 16, 0, 0);
}
static __device__ __forceinline__ u32 pkrtz(float a, float b) {
    auto h = __builtin_amdgcn_cvt_pkrtz(a, b);
    return __builtin_bit_cast(u32, h);
}
#define MFMA16(a, b, c) __builtin_amdgcn_mfma_f32_16x16x32_f16((a), (b), (c), 0, 0, 0)

// ---------------- fused fp32 -> fp16 convert (x | w_qkv | w_proj) ----------------
__global__ void cvt_all_kernel(const float* __restrict__ x, const float* __restrict__ wq,
                               const float* __restrict__ wp, f16* __restrict__ dst) {
    const int NX = BSZ * NSEQ * EDIM;
    const int NWQ = 3 * EDIM * EDIM;
    int i = (blockIdx.x * blockDim.x + threadIdx.x) * 4;
    const float* s;
    int j;
    if (i < NX) { s = x; j = i; }
    else if (i < NX + NWQ) { s = wq; j = i - NX; }
    else { s = wp; j = i - NX - NWQ; }
    float4 v = *(const float4*)(s + j);
    half4 o = { (f16)v.x, (f16)v.y, (f16)v.z, (f16)v.w };
    *(half4*)(dst + i) = o;
}

// ---------------- GEMM: C[m][c] = sum_k A[m][k]*W[c][k] + bias[c] ----------------
// 128(M) x 128(N) x 32(K) tile, 256 threads / 4 waves (2M x 2N), 4x4 frags/wave.
// GRID BALANCE: gemm<0> active blocks = 64 m-rows x 12 active n-tiles = 768
// = exactly 3.0 blocks/CU (the old 256-wide tile gave 384 = 1.5/CU -> 2x
// serial tail, which capped every pipeline variant at ~45 us).
// Fragment-order LDS (lane-linear ds_read_b128, conflict-free), counted-vmcnt
// 2-buffer pipeline (r13 form), XCD-pinned grid. MODE 1: nkt = 2*active_heads.
template<int MODE>
__global__ __launch_bounds__(256) void gemm_kernel(
    const f16* __restrict__ A, const f16* __restrict__ Wt, const float* __restrict__ bias,
    f16* __restrict__ qbuf, f16* __restrict__ kbuf, f16* __restrict__ vbuf,
    float* __restrict__ outp, const int* __restrict__ activep, int Kd, int NCd)
{
    __shared__ __align__(16) f16 Ah[2][2][4][64][8];   // [buf][wrh][fm][lane][8] 16 KB
    __shared__ __align__(16) f16 Bh[2][2][4][64][8];   // [buf][wch][fn][lane][8] 16 KB

    constexpr int K = EDIM;           // 768 for both GEMMs
    constexpr int NKT = K / 32;       // 24
    constexpr int NB = (MODE == 0) ? 18 : 6;   // 128-wide col tiles

    const int lin = blockIdx.x;
    const int xcd = lin & 7, pos = lin >> 3;
    const int bx = pos % NB;
    const int my = xcd + (pos / NB) * 8;
    const int c0 = bx * 128;
    const int m0 = my * 128;
    const int ah = *activep;
    if (MODE == 0) {
        if (((c0 % EDIM) >> 6) >= ah) return;   // both heads of this tile masked
    }
    const int nkt = (MODE == 1) ? (2 * ah) : NKT;   // MODE 1: skip zero ctx cols
    const int tid = threadIdx.x;
    const int lane = tid & 63;
    const int wid  = tid >> 6;        // 0..3
    const int wr = wid >> 1;          // M half (0..1)
    const int wc = wid & 1;           // N half (0..1)
    const int r16 = lane & 15, rg = lane >> 4;

    f32x4 acc[4][4];
#pragma unroll
    for (int i = 0; i < 4; ++i)
#pragma unroll
        for (int j = 0; j < 4; ++j)
            acc[i][j] = f32x4{0.f, 0.f, 0.f, 0.f};

    // staging: 8 A-slabs + 8 B-slabs per K-step (slab s -> wrh=s>>2, fm=s&3);
    // wave wid stages A-slabs {2wid, 2wid+1} and B-slabs {2wid, 2wid+1}
    const int s0 = 2 * wid, s1 = 2 * wid + 1;
    const f16* gA0 = A  + (size_t)(m0 + (s0 >> 2) * 64 + (s0 & 3) * 16 + r16) * K + rg * 8;
    const f16* gA1 = A  + (size_t)(m0 + (s1 >> 2) * 64 + (s1 & 3) * 16 + r16) * K + rg * 8;
    const f16* gB0 = Wt + (size_t)(c0 + (s0 >> 2) * 64 + (s0 & 3) * 16 + r16) * K + rg * 8;
    const f16* gB1 = Wt + (size_t)(c0 + (s1 >> 2) * 64 + (s1 & 3) * 16 + r16) * K + rg * 8;

    auto stage = [&](int buf, int kt) {
        gload16(gA0 + kt * 32, &Ah[buf][s0 >> 2][s0 & 3][0][0]);
        gload16(gA1 + kt * 32, &Ah[buf][s1 >> 2][s1 & 3][0][0]);
        gload16(gB0 + kt * 32, &Bh[buf][s0 >> 2][s0 & 3][0][0]);
        gload16(gB1 + kt * 32, &Bh[buf][s1 >> 2][s1 & 3][0][0]);
    };

    if (nkt > 0) stage(0, 0);
    if (nkt > 1) stage(1, 1);
    asm volatile("s_waitcnt vmcnt(4)" ::: "memory");   // tile 0 landed; tile 1 in flight
    __builtin_amdgcn_s_barrier();
    __builtin_amdgcn_sched_barrier(0);

#pragma unroll 1
    for (int kt = 0; kt < nkt; ++kt) {
        const int cur = kt & 1;
        half8 af[4], bf[4];
#pragma unroll
        for (int f = 0; f < 4; ++f) {
            af[f] = *(const half8*)&Ah[cur][wr][f][lane][0];
            bf[f] = *(const half8*)&Bh[cur][wc][f][lane][0];
        }
        asm volatile("s_waitcnt lgkmcnt(0)" ::: "memory");   // my reads drained
        __builtin_amdgcn_sched_barrier(0);
        __builtin_amdgcn_s_barrier();            // barrier1: ALL waves done with buf[cur]
        __builtin_amdgcn_sched_barrier(0);
        if (kt + 2 < nkt) stage(cur, kt + 2);    // refill the buffer just vacated
        __builtin_amdgcn_sched_barrier(0);
        __builtin_amdgcn_s_setprio(1);
#pragma unroll
        for (int fm = 0; fm < 4; ++fm)
#pragma unroll
            for (int fn = 0; fn < 4; ++fn)
                acc[fm][fn] = MFMA16(af[fm], bf[fn], acc[fm][fn]);
        __builtin_amdgcn_s_setprio(0);
        if (kt + 1 < nkt) {
            if (kt + 2 < nkt) asm volatile("s_waitcnt vmcnt(4)" ::: "memory");  // kt+1 landed
            else              asm volatile("s_waitcnt vmcnt(0)" ::: "memory");  // drain tail
            __builtin_amdgcn_s_barrier();        // barrier2: buf[cur^1] published
            __builtin_amdgcn_sched_barrier(0);
        }
    }

    // epilogue: C/D layout col=lane&15, row=(lane>>4)*4+reg
#pragma unroll
    for (int fn = 0; fn < 4; ++fn) {
        const int c = c0 + wc * 64 + fn * 16 + r16;
        const float bv = bias[c];
        const bool colActive = (MODE == 1) || (((c % EDIM) >> 6) < ah);
#pragma unroll
        for (int fm = 0; fm < 4; ++fm) {
            const int mbase = m0 + wr * 64 + fm * 16 + rg * 4;
#pragma unroll
            for (int r = 0; r < 4; ++r) {
                const float val = acc[fm][fn][r] + bv;
                const int m = mbase + r;
                if (MODE == 1) {
                    outp[(size_t)m * EDIM + c] = val;
                } else if (colActive) {
                    const int s  = c / EDIM;
                    const int cc = c % EDIM;
                    const int hh = cc >> 6, d = cc & 63;
                    const int bb = m >> 10, n = m & 1023;
                    f16* dst = (s == 0) ? qbuf : ((s == 1) ? kbuf : vbuf);
                    dst[(((size_t)bb * NH + hh) * NSEQ + n) * DH + d] = (f16)val;
                }
            }
        }
    }
}

// ---------------- V transpose: vbuf [b][h][n][d] -> vtb [b][h][d][n] ----------------
__global__ __launch_bounds__(256) void vtrans_kernel(const f16* __restrict__ vbuf,
                                                     f16* __restrict__ vtb,
                                                     const int* __restrict__ activep) {
    const int b = blockIdx.z, h = blockIdx.y;
    if (h >= *activep) return;
    const int n0 = blockIdx.x * 64;
    __shared__ __align__(16) f16 T[64][72];
    const f16* src = vbuf + (((size_t)b * NH + h) * NSEQ + n0) * DH;
    f16* dst = vtb + ((size_t)b * NH + h) * DH * NSEQ;
    const int t = threadIdx.x;
    const int rn = t >> 2, rc = t & 3;
    *(half8*)&T[rn][rc * 16]     = *(const half8*)&src[(size_t)rn * DH + rc * 16];
    *(half8*)&T[rn][rc * 16 + 8] = *(const half8*)&src[(size_t)rn * DH + rc * 16 + 8];
    __syncthreads();
    const int d = t >> 2, nc = (t & 3) * 16;
    half8 o0, o1;
#pragma unroll
    for (int j = 0; j < 8; ++j) {
        o0[j] = T[nc + j][d];
        o1[j] = T[nc + 8 + j][d];
    }
    *(half8*)&dst[(size_t)d * NSEQ + n0 + nc]     = o0;
    *(half8*)&dst[(size_t)d * NSEQ + n0 + nc + 8] = o1;
}

// ---------------- flash attention: 128-row Q block, 8 waves share K/V tiles ----------------
__global__ __launch_bounds__(512) void attn_kernel(
    const f16* __restrict__ qbuf, const f16* __restrict__ kbuf, const f16* __restrict__ vtb,
    f16* __restrict__ ctx, const int* __restrict__ activep)
{
    __shared__ __align__(16) f16 Kh[2][64][64];   // 16 KB
    __shared__ __align__(16) f16 Vh[2][64][64];   // 16 KB  (swizzled V^T tile: row d, 64 k)
    __shared__ __align__(16) f16 Ph[8][16][64];   // 16 KB  per-wave P, swizzled

    const int b = blockIdx.z, h = blockIdx.y;
    const int q0 = blockIdx.x * 128;
    const int tid = threadIdx.x, lane = tid & 63, wid = tid >> 6;

    if (h >= *activep) return;   // masked head: ctx region never read (gemm1 truncated)

    const size_t hb = (((size_t)b * NH + h) * NSEQ) * DH;
    const f16* Q  = qbuf + hb;
    const char* Kp = (const char*)(kbuf + hb);
    const char* Vp = (const char*)(vtb + hb);   // rows d, stride NSEQ*2 bytes

    const int ql = lane & 15;
    const int g  = lane >> 4;
    const int q7 = ql & 7;

    // Q B-fragment, pre-scaled by 0.125*log2(e): scores arrive in log2 domain,
    // so softmax uses native exp2 (no per-score multiply).
    half8 qb0, qb1;
    {
        const f16 qsc = (f16)0.18033688f;
        const f16* qp = Q + (size_t)(q0 + wid * 16 + ql) * DH + g * 8;
        qb0 = *(const half8*)qp        * qsc;
        qb1 = *(const half8*)(qp + 32) * qsc;
    }
    const half8 ones = { (f16)1, (f16)1, (f16)1, (f16)1, (f16)1, (f16)1, (f16)1, (f16)1 };

    // staging: waves 0-3 stage K (16 rows each), waves 4-7 stage V^T (16 rows each)
    // pre-swizzled global source (chunk ^= row&7), linear gload_lds dest
    const int srow8 = lane >> 3;                 // row within 8-row group
    const int schk  = (lane & 7) ^ srow8;        // swizzled source chunk
    const int qh4   = wid & 3;                   // 16-row chunk id

    auto stage = [&](int buf, int kt) {
        if (wid < 4) {
            const char* kb = Kp + (size_t)kt * 8192;        // 64 rows * 128B
#pragma unroll
            for (int i = 0; i < 2; ++i) {
                const int r = qh4 * 16 + i * 8 + srow8;
                gload16(kb + (size_t)r * 128 + schk * 16, &Kh[buf][qh4 * 16 + i * 8][0]);
            }
        } else {
#pragma unroll
            for (int i = 0; i < 2; ++i) {
                const int r = qh4 * 16 + i * 8 + srow8;
                gload16(Vp + (size_t)r * (NSEQ * 2) + (size_t)kt * 128 + schk * 16,
                        &Vh[buf][qh4 * 16 + i * 8][0]);
            }
        }
    };

    f32x4 oacc[4];
#pragma unroll
    for (int i = 0; i < 4; ++i) oacc[i] = f32x4{0.f, 0.f, 0.f, 0.f};
    f32x4 lacc = f32x4{0.f, 0.f, 0.f, 0.f};   // row-sums of P, same row layout as oacc
    float mr = -INFINITY;

    char* prow = (char*)&Ph[wid][ql][0];

    stage(0, 0);
    const int NT = NSEQ / 64;
    for (int kt = 0; kt < NT; ++kt) {
        const int cur = kt & 1;
        __syncthreads();                     // cur's loads landed; prev reads done
        if (kt + 1 < NT) stage(cur ^ 1, kt + 1);   // fly during compute below

        // S^T = K Q^T : st[s][r] = S^T[k=16s+4g+r][q=ql]  (log2 domain)
        f32x4 st[4];
        __builtin_amdgcn_s_setprio(1);
#pragma unroll
        for (int s = 0; s < 4; ++s) {
            f32x4 t = f32x4{0.f, 0.f, 0.f, 0.f};
            t = MFMA16(*(const half8*)((const char*)&Kh[cur][16 * s + ql][0] + ((g ^ q7) << 4)),       qb0, t);
            t = MFMA16(*(const half8*)((const char*)&Kh[cur][16 * s + ql][0] + (((4 | g) ^ q7) << 4)), qb1, t);
            st[s] = t;
        }
        __builtin_amdgcn_s_setprio(0);

        // row max: nested triples -> v_max3_f32, then 2 shuffles
        float a0 = fmaxf(fmaxf(st[0][0], st[0][1]), st[0][2]);
        float a1 = fmaxf(fmaxf(st[0][3], st[1][0]), st[1][1]);
        float a2 = fmaxf(fmaxf(st[1][2], st[1][3]), st[2][0]);
        float a3 = fmaxf(fmaxf(st[2][1], st[2][2]), st[2][3]);
        float a4 = fmaxf(fmaxf(st[3][0], st[3][1]), st[3][2]);
        float pmax = fmaxf(fmaxf(fmaxf(a0, a1), fmaxf(a2, a3)), fmaxf(a4, st[3][3]));
        pmax = fmaxf(pmax, __shfl_xor(pmax, 16));
        pmax = fmaxf(pmax, __shfl_xor(pmax, 32));

        // online softmax (log2 domain, unconditional rescale)
        const float mnew = fmaxf(mr, pmax);
        const float sc = exp2f(mr - mnew);
#pragma unroll
        for (int s = 0; s < 4; ++s)
#pragma unroll
            for (int r = 0; r < 4; ++r)
                st[s][r] = exp2f(st[s][r] - mnew);   // native v_exp_f32
        mr = mnew;

        // rescale O and l accumulators (C rows are q = 4g + r)
#pragma unroll
        for (int r = 0; r < 4; ++r) {
            const float scr = __shfl(sc, (g << 2) | r);
            oacc[0][r] *= scr; oacc[1][r] *= scr; oacc[2][r] *= scr; oacc[3][r] *= scr;
            lacc[r] *= scr;
        }

        // P -> per-wave swizzled LDS: row ql, halves k = 16s+4g .. +3
#pragma unroll
        for (int s = 0; s < 4; ++s) {
            u32x2 w = { pkrtz(st[s][0], st[s][1]), pkrtz(st[s][2], st[s][3]) };
            *(u32x2*)(prow + ((32 * s + 8 * g) ^ (q7 << 4))) = w;
        }
        const half8 pa0 = *(const half8*)(prow + ((16 * g) ^ (q7 << 4)));
        const half8 pa1 = *(const half8*)(prow + ((64 + 16 * g) ^ (q7 << 4)));

        // O += P V ; l += P 1  (row-sum via ones-MFMA, no shuffles)
        __builtin_amdgcn_s_setprio(1);
        lacc = MFMA16(pa0, ones, lacc);
        lacc = MFMA16(pa1, ones, lacc);
#pragma unroll
        for (int db = 0; db < 4; ++db) {
            oacc[db] = MFMA16(pa0, *(const half8*)((const char*)&Vh[cur][16 * db + ql][0] + ((g ^ q7) << 4)),       oacc[db]);
            oacc[db] = MFMA16(pa1, *(const half8*)((const char*)&Vh[cur][16 * db + ql][0] + (((4 | g) ^ q7) << 4)), oacc[db]);
        }
        __builtin_amdgcn_s_setprio(0);
    }

    // epilogue: rows q = 4g + r, cols d = db*16 + ql ; l already in row layout
#pragma unroll
    for (int r = 0; r < 4; ++r) {
        const float li = 1.0f / lacc[r];
        const int n = q0 + wid * 16 + (g << 2) + r;
#pragma unroll
        for (int db = 0; db < 4; ++db)
            ctx[((size_t)b * NSEQ + n) * EDIM + h * DH + db * 16 + ql] = (f16)(oacc[db][r] * li);
    }
}

// ---------------- launch ----------------
extern "C" void kernel_launch(void* const* d_in, const int* in_sizes, int n_in,
                              void* d_out, int out_size, void* d_ws, size_t ws_size,
                              hipStream_t stream) {
    const float* x      = (const float*)d_in[0];
    const float* w_qkv  = (const float*)d_in[1];
    const float* b_qkv  = (const float*)d_in[2];
    const float* w_proj = (const float*)d_in[3];
    const float* b_proj = (const float*)d_in[4];
    const int*   active = (const int*)d_in[5];
    float* out = (float*)d_out;

    char* ws = (char*)d_ws;
    const size_t n_x  = (size_t)BSZ * NSEQ * EDIM;       // 6291456
    const size_t n_wq = (size_t)3 * EDIM * EDIM;         // 1769472
    const size_t n_wp = (size_t)EDIM * EDIM;             // 589824
    const size_t n_hd = (size_t)BSZ * NH * NSEQ * DH;    // 6291456 per q/k/v

    f16* xh   = (f16*)ws;
    f16* wqh  = xh + n_x;
    f16* wph  = wqh + n_wq;
    f16* qh   = wph + n_wp;
    f16* kh   = qh + n_hd;
    f16* vh   = kh + n_hd;
    f16* ctxh = vh + n_hd;
    f16* vtb  = xh;   // alias: xh is dead after gemm<0>; n_x == n_hd

    const size_t n_cvt = n_x + n_wq + n_wp;
    cvt_all_kernel<<<(int)(n_cvt / 4 / 256), 256, 0, stream>>>(x, w_qkv, w_proj, xh);

    gemm_kernel<0><<<dim3(64 * 18), 256, 0, stream>>>(
        xh, wqh, b_qkv, qh, kh, vh, nullptr, active, EDIM, 3 * EDIM);

    vtrans_kernel<<<dim3(NSEQ / 64, NH, BSZ), 256, 0, stream>>>(vh, vtb, active);

    attn_kernel<<<dim3(NSEQ / 128, NH, BSZ), 512, 0, stream>>>(qh, kh, vtb, ctxh, active);

    gemm_kernel<1><<<dim3(64 * 6), 256, 0, stream>>>(
        ctxh, wph, b_proj, nullptr, nullptr, nullptr, out, active, EDIM, EDIM);
}